// Round 3
// baseline (352.201 us; speedup 1.0000x reference)
//
#include <hip/hip_runtime.h>

// Shift-TCN fused pipeline v4, MI355X (gfx950).
// [memset acc=0]
// [K12] single x pass: reg-batched loads (16 f4 in flight/thread, MLP fix) ->
//       BN1 stats from regs + bf16 LDS transpose -> shift_raw -> ht[j][c] bf16
// [Kp ] params: W'b = bf16(W*sc), b2all/S0/S63 rank corrections
// [K3 ] MFMA GEMM o-tile=256, j-tile=128, K-step=64 (64 MFMA/barrier, 48KB LDS),
//       split epilogue (two 128-o halves) with LDS-transposed coalesced y stores
// [K4 ] BN2 analytic stats (S,Q,P,Y0,Q0,Y63,Q63) streaming, 1-deep prefetch
// [K5 ] shift_out + BN2 affine div-free -> out (fp32)

#define EPSV 1e-5f
constexpr int Nn = 64, Cc = 256, Tt = 64, Vv = 25;
constexpr int TV = Tt * Vv;          // 1600
constexpr int CTV = Cc * TV;         // 409600
constexpr float Minv = 1.0f / (Nn * TV);   // 1/102400

typedef short short8 __attribute__((ext_vector_type(8)));
typedef float floatx4 __attribute__((ext_vector_type(4)));

__device__ __forceinline__ unsigned short f2bf(float f) {
    unsigned int u = __builtin_bit_cast(unsigned int, f);
    u += 0x7FFFu + ((u >> 16) & 1u);      // round-to-nearest-even
    return (unsigned short)(u >> 16);
}
__device__ __forceinline__ float bflo(unsigned int w) {
    return __builtin_bit_cast(float, w << 16);
}
__device__ __forceinline__ float bfhi(unsigned int w) {
    return __builtin_bit_cast(float, w & 0xFFFF0000u);
}
__device__ __forceinline__ void unp8v(uint4 u, float* o) {
    o[0] = bflo(u.x); o[1] = bfhi(u.x); o[2] = bflo(u.y); o[3] = bfhi(u.y);
    o[4] = bflo(u.z); o[5] = bfhi(u.z); o[6] = bflo(u.w); o[7] = bfhi(u.w);
}
__device__ __forceinline__ void gload_lds16(const void* g, void* l) {
    __builtin_amdgcn_global_load_lds((const __attribute__((address_space(1))) void*)g,
                                     (__attribute__((address_space(3))) void*)l, 16, 0, 0);
}

// ------- K12: fused BN1 stats + shift_raw + bf16 transpose-store -------
// grid (4 cgrp(64ch), 8 ttile(200tv), 64 n), block 256.
__global__ __launch_bounds__(256) void k_stats_shift(const float* __restrict__ x,
                                                     const float* __restrict__ theta,
                                                     float* __restrict__ sacc,
                                                     float* __restrict__ qacc,
                                                     unsigned short* __restrict__ ht) {
    int c0 = blockIdx.x * 64;
    int E0 = blockIdx.y * 200;
    int n  = blockIdx.z;
    int tid = threadIdx.x;
    __shared__ __attribute__((aligned(16))) unsigned short xt[256][68];
    __shared__ int   pd[64];
    __shared__ float pf[64];
    if (tid < 64) {
        float th = theta[c0 + tid];
        float fd = floorf(th);
        pd[tid] = (int)fd;        // d in {-1, 0} for theta in [-1,1)
        pf[tid] = th - fd;
    }
    int lo = E0 - 28; if (lo < 0) lo = 0;
    int hi = E0 + 228; if (hi > 1600) hi = 1600;
    int ldsoff = lo - (E0 - 28);             // 0 or 28, multiple of 4
    int nf4 = (hi - lo) >> 2;
    {   // reg-batched loads: issue ALL 16 float4 loads, then process from regs
        int cp = tid >> 3, li = tid & 7;
        int ca = 2 * cp;
        const float4* xr0 = (const float4*)(x + (size_t)n * CTV + (size_t)(c0 + ca) * TV + lo);
        const float4* xr1 = xr0 + (TV >> 2);
        float4 v0[8], v1[8];
#pragma unroll
        for (int s = 0; s < 8; ++s) {
            int i = li + s * 8;
            if (i < nf4) { v0[s] = xr0[i]; v1[s] = xr1[i]; }
        }
        float s0 = 0.f, q0 = 0.f, s1 = 0.f, q1 = 0.f;
#pragma unroll
        for (int s = 0; s < 8; ++s) {
            int i = li + s * 8;
            if (i < nf4) {
                int r = ldsoff + i * 4;
#pragma unroll
                for (int k = 0; k < 4; ++k) {
                    float a = ((const float*)&v0[s])[k];
                    float b = ((const float*)&v1[s])[k];
                    if ((unsigned)(r + k - 28) < 200u) {
                        s0 += a; q0 += a * a; s1 += b; q1 += b * b;
                    }
                    unsigned int pk = (unsigned int)f2bf(a) | (((unsigned int)f2bf(b)) << 16);
                    *(unsigned int*)&xt[r + k][ca] = pk;
                }
            }
        }
        for (int off = 4; off; off >>= 1) {
            s0 += __shfl_down(s0, off); q0 += __shfl_down(q0, off);
            s1 += __shfl_down(s1, off); q1 += __shfl_down(q1, off);
        }
        if (li == 0) {
            atomicAdd(&sacc[c0 + ca], s0);     atomicAdd(&qacc[c0 + ca], q0);
            atomicAdd(&sacc[c0 + ca + 1], s1); atomicAdd(&qacc[c0 + ca + 1], q1);
        }
    }
    __syncthreads();
    // shift_raw + bf16 pack, store [j][c] 128B segments; no divides (tv masks)
    int cseg = tid & 7, er = tid >> 3;
    int cb = cseg * 8;
    int dk[8]; float fk[8];
#pragma unroll
    for (int k = 0; k < 8; ++k) { dk[k] = pd[cb + k]; fk[k] = pf[cb + k]; }
    for (int it = 0; it < 7; ++it) {
        int tv_l = er + it * 32;
        if (tv_l >= 200) break;
        int e = E0 + tv_l;
        float A8[8], B8[8], C8[8];
        {
            const unsigned short* rA = &xt[tv_l + 3][cb];    // tv-25 row
            const unsigned short* rB = &xt[tv_l + 28][cb];   // tv row
            const unsigned short* rC = &xt[tv_l + 53][cb];   // tv+25 row
            uint2 a0 = *(const uint2*)rA, a1 = *(const uint2*)(rA + 4);
            uint2 b0 = *(const uint2*)rB, b1 = *(const uint2*)(rB + 4);
            uint2 g0 = *(const uint2*)rC, g1 = *(const uint2*)(rC + 4);
            A8[0]=bflo(a0.x); A8[1]=bfhi(a0.x); A8[2]=bflo(a0.y); A8[3]=bfhi(a0.y);
            A8[4]=bflo(a1.x); A8[5]=bfhi(a1.x); A8[6]=bflo(a1.y); A8[7]=bfhi(a1.y);
            B8[0]=bflo(b0.x); B8[1]=bfhi(b0.x); B8[2]=bflo(b0.y); B8[3]=bfhi(b0.y);
            B8[4]=bflo(b1.x); B8[5]=bfhi(b1.x); B8[6]=bflo(b1.y); B8[7]=bfhi(b1.y);
            C8[0]=bflo(g0.x); C8[1]=bfhi(g0.x); C8[2]=bflo(g0.y); C8[3]=bfhi(g0.y);
            C8[4]=bflo(g1.x); C8[5]=bfhi(g1.x); C8[6]=bflo(g1.y); C8[7]=bfhi(g1.y);
        }
        unsigned int w4[4];
#pragma unroll
        for (int k = 0; k < 8; ++k) {
            int d = dk[k]; float f = fk[k];
            float x0 = (d < 0) ? A8[k] : B8[k];
            float x1 = (d < 0) ? B8[k] : C8[k];
            int e0 = e + 25 * d;
            float v0 = ((unsigned)e0 < 1600u) ? x0 : 0.f;
            float v1 = ((unsigned)(e0 + 25) < 1600u) ? x1 : 0.f;
            unsigned short hb = f2bf(v0 + f * (v1 - v0));
            if (k & 1) w4[k >> 1] |= ((unsigned int)hb) << 16;
            else       w4[k >> 1] = hb;
        }
        uint4 st = { w4[0], w4[1], w4[2], w4[3] };
        *(uint4*)(ht + (size_t)(n * 1600 + e) * 256 + c0 + cb) = st;
    }
}

// ------- Kp: finalize BN1 params; W'b = bf16(W*sc); rank-corrections -------
__global__ __launch_bounds__(256) void k_params(const float* __restrict__ w,
                                                const float* __restrict__ bias,
                                                const float* __restrict__ sacc,
                                                const float* __restrict__ qacc,
                                                const float* __restrict__ g,
                                                const float* __restrict__ b,
                                                const float* __restrict__ theta,
                                                unsigned short* __restrict__ wb,
                                                float* __restrict__ b2all,
                                                float* __restrict__ s0v,
                                                float* __restrict__ s63v) {
    int o = blockIdx.x, c = threadIdx.x;
    float mean = sacc[c] * Minv;
    float var  = qacc[c] * Minv - mean * mean;
    float sc = g[c] * rsqrtf(var + EPSV);
    float tc = b[c] - mean * sc;
    float th = theta[c];
    float fd = floorf(th);
    int d = (int)fd;
    float f = th - fd;
    float wv = w[o * 256 + c];
    wb[o * 256 + c] = f2bf(wv * sc);
    float wtc = wv * tc;
    float r0  = (d < 0) ? wtc * (1.f - f) : 0.f;   // t==0 correction (d==-1)
    float r63 = (d == 0) ? wtc * f : 0.f;          // t==63 correction (d==0)
    for (int off = 32; off; off >>= 1) {
        wtc += __shfl_down(wtc, off);
        r0  += __shfl_down(r0, off);
        r63 += __shfl_down(r63, off);
    }
    __shared__ float aux[3][4];
    if ((c & 63) == 0) { int wi = c >> 6; aux[0][wi] = wtc; aux[1][wi] = r0; aux[2][wi] = r63; }
    __syncthreads();
    if (c == 0) {
        b2all[o] = bias[o] + aux[0][0] + aux[0][1] + aux[0][2] + aux[0][3];
        s0v[o]  = aux[1][0] + aux[1][1] + aux[1][2] + aux[1][3];
        s63v[o] = aux[2][0] + aux[2][1] + aux[2][2] + aux[2][3];
    }
}

// ------- K3: y = relu(W' ht + bias2). o-tile=256, j-tile=128, K-step=64 -------
// grid (800), block 256 (4 waves). LDS 48KB: A[256][64] + B[128][64] bf16,
// reused as C-tile [128][136] in two o-half epilogue passes.
__global__ __launch_bounds__(256) void k_gemm(const unsigned short* __restrict__ ht,
                                              const unsigned short* __restrict__ wb,
                                              const float* __restrict__ b2all,
                                              const float* __restrict__ s0v,
                                              const float* __restrict__ s63v,
                                              unsigned short* __restrict__ y) {
    int j0 = blockIdx.x * 128;
    int tid = threadIdx.x;
    int w = tid >> 6, lane = tid & 63;
    int quad = lane >> 4, l16 = lane & 15;
    __shared__ __attribute__((aligned(16))) unsigned short smem[256 * 64 + 128 * 64]; // 49,152 B
    unsigned short* A = smem;              // [256 o][64 k]
    unsigned short* B = smem + 256 * 64;   // [128 j][64 k]
    floatx4 acc[4][8] = {};
    int srow8 = lane >> 3;                 // 0..7
    int skc = (lane & 7) * 8;              // shorts 0..56
    const unsigned short* wp = wb + (size_t)(w * 64 + srow8) * 256 + skc;
    const unsigned short* hp = ht + (size_t)(j0 + w * 32 + srow8) * 256 + skc;
    for (int k0 = 0; k0 < 256; k0 += 64) {
        __syncthreads();                   // prev iter's frag reads done
#pragma unroll
        for (int a = 0; a < 8; ++a)
            gload_lds16(wp + (size_t)a * 8 * 256 + k0, A + (w * 64 + a * 8) * 64);
#pragma unroll
        for (int a = 0; a < 4; ++a)
            gload_lds16(hp + (size_t)a * 8 * 256 + k0, B + (w * 32 + a * 8) * 64);
        __syncthreads();                   // vmcnt drained at barrier
#pragma unroll
        for (int kk = 0; kk < 2; ++kk) {
            short8 af[4], bf[8];
#pragma unroll
            for (int m = 0; m < 4; ++m)
                af[m] = *(const short8*)&A[(w * 64 + m * 16 + l16) * 64 + kk * 32 + quad * 8];
#pragma unroll
            for (int jt = 0; jt < 8; ++jt)
                bf[jt] = *(const short8*)&B[(jt * 16 + l16) * 64 + kk * 32 + quad * 8];
#pragma unroll
            for (int m = 0; m < 4; ++m)
#pragma unroll
                for (int jt = 0; jt < 8; ++jt)
                    acc[m][jt] = __builtin_amdgcn_mfma_f32_16x16x32_bf16(af[m], bf[jt], acc[m][jt], 0, 0, 0);
        }
    }
    __syncthreads();                       // before overwriting smem as C-tile
    unsigned short* Cl = smem;             // [128 o][136 pad] bf16
    int li = tid & 15, orow = tid >> 4;
#pragma unroll
    for (int p = 0; p < 2; ++p) {
        if ((w >> 1) == p) {
            int rowbase = (w & 1) * 64;
#pragma unroll
            for (int m = 0; m < 4; ++m) {
                int ob = p * 128 + (w & 1) * 64 + m * 16 + quad * 4;
#pragma unroll
                for (int r = 0; r < 4; ++r) {
                    int o = ob + r;
                    float bb = b2all[o], e0 = s0v[o], e63 = s63v[o];
                    int lrow = rowbase + m * 16 + quad * 4 + r;
#pragma unroll
                    for (int jt = 0; jt < 8; ++jt) {
                        int jj = j0 + jt * 16;
                        int nn = jj / 1600;
                        int tvb = jj - nn * 1600 + l16;
                        float bia = bb - (tvb < 25 ? e0 : 0.f) - (tvb >= 1575 ? e63 : 0.f);
                        float v = acc[m][jt][r] + bia;
                        v = v > 0.f ? v : 0.f;
                        Cl[lrow * 136 + jt * 16 + l16] = f2bf(v);
                    }
                }
            }
        }
        __syncthreads();
#pragma unroll
        for (int pass = 0; pass < 8; ++pass) {
            int ol = orow + pass * 16;
            uint4 vv = *(const uint4*)&Cl[ol * 136 + li * 8];
            int o = p * 128 + ol;
            int j = j0 + li * 8;
            int nn = j / 1600;
            int tv = j - nn * 1600;
            *(uint4*)(y + (size_t)nn * CTV + (size_t)o * TV + tv) = vv;
        }
        if (p == 0) __syncthreads();
    }
}

// ------- K4: BN2 analytic partial sums over y (no gather). grid (8 ngrp, 256 o) -------
// acc7: [7][256] = S, Q, P, Y0, Q0, Y63, Q63. 1-deep n prefetch for MLP.
__global__ __launch_bounds__(256) void k_bn2_stats(const unsigned short* __restrict__ y,
                                                   float* __restrict__ acc7) {
    int o = blockIdx.y, ng = blockIdx.x, tid = threadIdx.x;
    float S = 0.f, Q = 0.f, P = 0.f, Y0 = 0.f, Q0 = 0.f, Y63 = 0.f, Q63 = 0.f;
    if (tid < 200) {
        int e = tid * 8;
        int eB = e + 24; if (eB > 1592) eB = 1592;
        int eC = e + 32; if (eC > 1592) eC = 1592;
        const unsigned short* base0 = y + (size_t)(ng * 8) * CTV + (size_t)o * TV;
        uint4 ua = *(const uint4*)(base0 + e);
        uint4 ub = *(const uint4*)(base0 + eB);
        uint4 uc = *(const uint4*)(base0 + eC);
        for (int nn = 0; nn < 8; ++nn) {
            uint4 na, nb, nc;
            if (nn < 7) {
                const unsigned short* row = base0 + (size_t)(nn + 1) * CTV;
                na = *(const uint4*)(row + e);
                nb = *(const uint4*)(row + eB);
                nc = *(const uint4*)(row + eC);
            }
            float a[8], b[8], c[8];
            unp8v(ua, a); unp8v(ub, b); unp8v(uc, c);
#pragma unroll
            for (int k = 0; k < 8; ++k) {
                float v = a[k];
                S += v; Q += v * v;
                float vn = (k < 7) ? b[k + 1] : c[0];     // y[e+k+25]
                if (e + k < 1575) P += v * vn;
            }
            if (e < 32) {
#pragma unroll
                for (int k = 0; k < 8; ++k)
                    if (e + k < 25) { Y0 += a[k]; Q0 += a[k] * a[k]; }
            }
            if (e >= 1568) {
#pragma unroll
                for (int k = 0; k < 8; ++k)
                    if (e + k >= 1575) { Y63 += a[k]; Q63 += a[k] * a[k]; }
            }
            ua = na; ub = nb; uc = nc;
        }
    }
    for (int off = 32; off; off >>= 1) {
        S += __shfl_down(S, off); Q += __shfl_down(Q, off); P += __shfl_down(P, off);
        Y0 += __shfl_down(Y0, off); Q0 += __shfl_down(Q0, off);
        Y63 += __shfl_down(Y63, off); Q63 += __shfl_down(Q63, off);
    }
    if ((tid & 63) == 0) {
        atomicAdd(&acc7[o], S);           atomicAdd(&acc7[256 + o], Q);
        atomicAdd(&acc7[512 + o], P);     atomicAdd(&acc7[768 + o], Y0);
        atomicAdd(&acc7[1024 + o], Q0);   atomicAdd(&acc7[1280 + o], Y63);
        atomicAdd(&acc7[1536 + o], Q63);
    }
}

// ------- K5: out = BN2(shift_out(y)) fp32, div-free masks. grid (64 n, 256 o) -------
__global__ __launch_bounds__(256) void k_bn2_apply(const unsigned short* __restrict__ y,
                                                   const float* __restrict__ theta,
                                                   const float* __restrict__ acc7,
                                                   const float* __restrict__ g,
                                                   const float* __restrict__ b,
                                                   float* __restrict__ out) {
    int o = blockIdx.y, n = blockIdx.x, tid = threadIdx.x;
    float th = theta[o];
    float fd = floorf(th);
    int d = (int)fd;
    float f = th - fd;
    float S = acc7[o], Q = acc7[256 + o], P = acc7[512 + o];
    float Y0 = acc7[768 + o], Q0 = acc7[1024 + o], Y63 = acc7[1280 + o], Q63 = acc7[1536 + o];
    float omf = 1.f - f;
    float sz, qz;
    if (d < 0) { sz = S - omf * Y63; qz = omf * omf * (Q - Q63) + f * f * Q + 2.f * f * omf * P; }
    else       { sz = S - f * Y0;    qz = omf * omf * Q + f * f * (Q - Q0) + 2.f * f * omf * P; }
    float mean = sz * Minv;
    float var = qz * Minv - mean * mean;
    float sc = g[o] * rsqrtf(var + EPSV);
    float tc = b[o] - mean * sc;
    if (tid >= 200) return;
    int e = tid * 8;
    const unsigned short* row = y + (size_t)n * CTV + (size_t)o * TV;
    float a0[8], a1[8];
    if (d < 0) {
        int eA = e - 32; if (eA < 0) eA = 0;
        int eB = e - 24; if (eB < 0) eB = 0;
        float A[8], B[8], M[8];
        unp8v(*(const uint4*)(row + eA), A);
        unp8v(*(const uint4*)(row + eB), B);
        unp8v(*(const uint4*)(row + e), M);
        a0[0] = (e >= 25) ? A[7] : 0.f;     // y[e-25]
#pragma unroll
        for (int k = 1; k < 8; ++k) a0[k] = (e + k >= 25) ? B[k - 1] : 0.f;
#pragma unroll
        for (int k = 0; k < 8; ++k) a1[k] = M[k];
    } else {
        int eB = e + 24; if (eB > 1592) eB = 1592;
        int eC = e + 32; if (eC > 1592) eC = 1592;
        float M[8], B[8], C[8];
        unp8v(*(const uint4*)(row + e), M);
        unp8v(*(const uint4*)(row + eB), B);
        unp8v(*(const uint4*)(row + eC), C);
#pragma unroll
        for (int k = 0; k < 8; ++k) a0[k] = M[k];
#pragma unroll
        for (int k = 0; k < 7; ++k) a1[k] = (e + k < 1575) ? B[k + 1] : 0.f;
        a1[7] = (e + 7 < 1575) ? C[0] : 0.f;
    }
    float4 r0, r1;
#pragma unroll
    for (int k = 0; k < 4; ++k) {
        ((float*)&r0)[k] = (omf * a0[k] + f * a1[k]) * sc + tc;
        ((float*)&r1)[k] = (omf * a0[k + 4] + f * a1[k + 4]) * sc + tc;
    }
    float* op = out + (size_t)n * CTV + (size_t)o * TV + e;
    *(float4*)op = r0;
    *(float4*)(op + 4) = r1;
}

extern "C" void kernel_launch(void* const* d_in, const int* in_sizes, int n_in,
                              void* d_out, int out_size, void* d_ws, size_t ws_size,
                              hipStream_t stream) {
    const float* x      = (const float*)d_in[0];
    const float* conv_w = (const float*)d_in[1];
    const float* conv_b = (const float*)d_in[2];
    const float* bn1_g  = (const float*)d_in[3];
    const float* bn1_b  = (const float*)d_in[4];
    const float* bn2_g  = (const float*)d_in[5];
    const float* bn2_b  = (const float*)d_in[6];
    const float* th_in  = (const float*)d_in[7];
    const float* th_out = (const float*)d_in[8];
    float* out = (float*)d_out;

    char* ws = (char*)d_ws;
    unsigned short* ht = (unsigned short*)ws;                   // 52,428,800 B
    unsigned short* yy = (unsigned short*)(ws + 52428800);      // 52,428,800 B
    unsigned short* wb = (unsigned short*)(ws + 104857600);     // 131,072 B
    float* sacc1 = (float*)(ws + 104988672);
    float* qacc1 = sacc1 + 256;
    float* acc7  = qacc1 + 256;          // 7*256
    float* b2all = acc7 + 7 * 256;
    float* s0v   = b2all + 256;
    float* s63v  = s0v + 256;

    hipMemsetAsync((void*)sacc1, 0, 9 * 256 * sizeof(float), stream);
    hipLaunchKernelGGL(k_stats_shift, dim3(4, 8, 64), dim3(256), 0, stream,
                       x, th_in, sacc1, qacc1, ht);
    hipLaunchKernelGGL(k_params, dim3(256), dim3(256), 0, stream,
                       conv_w, conv_b, sacc1, qacc1, bn1_g, bn1_b, th_in,
                       wb, b2all, s0v, s63v);
    hipLaunchKernelGGL(k_gemm, dim3(800), dim3(256), 0, stream,
                       ht, wb, b2all, s0v, s63v, yy);
    hipLaunchKernelGGL(k_bn2_stats, dim3(8, 256), dim3(256), 0, stream, yy, acc7);
    hipLaunchKernelGGL(k_bn2_apply, dim3(64, 256), dim3(256), 0, stream,
                       yy, th_out, acc7, bn2_g, bn2_b, out);
}

// Round 4
// 339.595 us; speedup vs baseline: 1.0371x; 1.0371x over previous
//
#include <hip/hip_runtime.h>

// Shift-TCN fused pipeline v5, MI355X (gfx950).
// [memset acc=0]
// [K12] single x pass: reg-batched loads -> BN1 stats + bf16 LDS transpose ->
//       shift_raw -> ht[j][c] bf16
// [Kp ] params: W'b = bf16(W*sc), b2all/S0/S63 rank corrections
// [K3 ] MFMA GEMM o=256, j=128, K-step=32, DOUBLE-BUFFERED LDS (2x24KB) with
//       raw-barrier 2-phase pipeline (stage overlaps MFMA), XOR-granule swizzle
//       (pre-swizzled global src for global_load_lds + swizzled frag reads),
//       split epilogue with LDS-transposed coalesced y stores
// [K4 ] BN2 analytic stats (S,Q,P,Y0,Q0,Y63,Q63) streaming, 1-deep prefetch
// [K5 ] shift_out + BN2 affine div-free -> out (fp32)

#define EPSV 1e-5f
constexpr int Nn = 64, Cc = 256, Tt = 64, Vv = 25;
constexpr int TV = Tt * Vv;          // 1600
constexpr int CTV = Cc * TV;         // 409600
constexpr float Minv = 1.0f / (Nn * TV);   // 1/102400

typedef short short8 __attribute__((ext_vector_type(8)));
typedef float floatx4 __attribute__((ext_vector_type(4)));

__device__ __forceinline__ unsigned short f2bf(float f) {
    unsigned int u = __builtin_bit_cast(unsigned int, f);
    u += 0x7FFFu + ((u >> 16) & 1u);      // round-to-nearest-even
    return (unsigned short)(u >> 16);
}
__device__ __forceinline__ float bflo(unsigned int w) {
    return __builtin_bit_cast(float, w << 16);
}
__device__ __forceinline__ float bfhi(unsigned int w) {
    return __builtin_bit_cast(float, w & 0xFFFF0000u);
}
__device__ __forceinline__ void unp8v(uint4 u, float* o) {
    o[0] = bflo(u.x); o[1] = bfhi(u.x); o[2] = bflo(u.y); o[3] = bfhi(u.y);
    o[4] = bflo(u.z); o[5] = bfhi(u.z); o[6] = bflo(u.w); o[7] = bfhi(u.w);
}
__device__ __forceinline__ void gload_lds16(const void* g, void* l) {
    __builtin_amdgcn_global_load_lds((const __attribute__((address_space(1))) void*)g,
                                     (__attribute__((address_space(3))) void*)l, 16, 0, 0);
}

// ------- K12: fused BN1 stats + shift_raw + bf16 transpose-store -------
// grid (4 cgrp(64ch), 8 ttile(200tv), 64 n), block 256.
__global__ __launch_bounds__(256) void k_stats_shift(const float* __restrict__ x,
                                                     const float* __restrict__ theta,
                                                     float* __restrict__ sacc,
                                                     float* __restrict__ qacc,
                                                     unsigned short* __restrict__ ht) {
    int c0 = blockIdx.x * 64;
    int E0 = blockIdx.y * 200;
    int n  = blockIdx.z;
    int tid = threadIdx.x;
    __shared__ __attribute__((aligned(16))) unsigned short xt[256][68];
    __shared__ int   pd[64];
    __shared__ float pf[64];
    if (tid < 64) {
        float th = theta[c0 + tid];
        float fd = floorf(th);
        pd[tid] = (int)fd;        // d in {-1, 0} for theta in [-1,1)
        pf[tid] = th - fd;
    }
    int lo = E0 - 28; if (lo < 0) lo = 0;
    int hi = E0 + 228; if (hi > 1600) hi = 1600;
    int ldsoff = lo - (E0 - 28);             // 0 or 28, multiple of 4
    int nf4 = (hi - lo) >> 2;
    {   // reg-batched loads: issue ALL 16 float4 loads, then process from regs
        int cp = tid >> 3, li = tid & 7;
        int ca = 2 * cp;
        const float4* xr0 = (const float4*)(x + (size_t)n * CTV + (size_t)(c0 + ca) * TV + lo);
        const float4* xr1 = xr0 + (TV >> 2);
        float4 v0[8], v1[8];
#pragma unroll
        for (int s = 0; s < 8; ++s) {
            int i = li + s * 8;
            if (i < nf4) { v0[s] = xr0[i]; v1[s] = xr1[i]; }
        }
        float s0 = 0.f, q0 = 0.f, s1 = 0.f, q1 = 0.f;
#pragma unroll
        for (int s = 0; s < 8; ++s) {
            int i = li + s * 8;
            if (i < nf4) {
                int r = ldsoff + i * 4;
#pragma unroll
                for (int k = 0; k < 4; ++k) {
                    float a = ((const float*)&v0[s])[k];
                    float b = ((const float*)&v1[s])[k];
                    if ((unsigned)(r + k - 28) < 200u) {
                        s0 += a; q0 += a * a; s1 += b; q1 += b * b;
                    }
                    unsigned int pk = (unsigned int)f2bf(a) | (((unsigned int)f2bf(b)) << 16);
                    *(unsigned int*)&xt[r + k][ca] = pk;
                }
            }
        }
        for (int off = 4; off; off >>= 1) {
            s0 += __shfl_down(s0, off); q0 += __shfl_down(q0, off);
            s1 += __shfl_down(s1, off); q1 += __shfl_down(q1, off);
        }
        if (li == 0) {
            atomicAdd(&sacc[c0 + ca], s0);     atomicAdd(&qacc[c0 + ca], q0);
            atomicAdd(&sacc[c0 + ca + 1], s1); atomicAdd(&qacc[c0 + ca + 1], q1);
        }
    }
    __syncthreads();
    // shift_raw + bf16 pack, store [j][c] 128B segments; no divides (tv masks)
    int cseg = tid & 7, er = tid >> 3;
    int cb = cseg * 8;
    int dk[8]; float fk[8];
#pragma unroll
    for (int k = 0; k < 8; ++k) { dk[k] = pd[cb + k]; fk[k] = pf[cb + k]; }
    for (int it = 0; it < 7; ++it) {
        int tv_l = er + it * 32;
        if (tv_l >= 200) break;
        int e = E0 + tv_l;
        float A8[8], B8[8], C8[8];
        {
            const unsigned short* rA = &xt[tv_l + 3][cb];    // tv-25 row
            const unsigned short* rB = &xt[tv_l + 28][cb];   // tv row
            const unsigned short* rC = &xt[tv_l + 53][cb];   // tv+25 row
            uint2 a0 = *(const uint2*)rA, a1 = *(const uint2*)(rA + 4);
            uint2 b0 = *(const uint2*)rB, b1 = *(const uint2*)(rB + 4);
            uint2 g0 = *(const uint2*)rC, g1 = *(const uint2*)(rC + 4);
            A8[0]=bflo(a0.x); A8[1]=bfhi(a0.x); A8[2]=bflo(a0.y); A8[3]=bfhi(a0.y);
            A8[4]=bflo(a1.x); A8[5]=bfhi(a1.x); A8[6]=bflo(a1.y); A8[7]=bfhi(a1.y);
            B8[0]=bflo(b0.x); B8[1]=bfhi(b0.x); B8[2]=bflo(b0.y); B8[3]=bfhi(b0.y);
            B8[4]=bflo(b1.x); B8[5]=bfhi(b1.x); B8[6]=bflo(b1.y); B8[7]=bfhi(b1.y);
            C8[0]=bflo(g0.x); C8[1]=bfhi(g0.x); C8[2]=bflo(g0.y); C8[3]=bfhi(g0.y);
            C8[4]=bflo(g1.x); C8[5]=bfhi(g1.x); C8[6]=bflo(g1.y); C8[7]=bfhi(g1.y);
        }
        unsigned int w4[4];
#pragma unroll
        for (int k = 0; k < 8; ++k) {
            int d = dk[k]; float f = fk[k];
            float x0 = (d < 0) ? A8[k] : B8[k];
            float x1 = (d < 0) ? B8[k] : C8[k];
            int e0 = e + 25 * d;
            float v0 = ((unsigned)e0 < 1600u) ? x0 : 0.f;
            float v1 = ((unsigned)(e0 + 25) < 1600u) ? x1 : 0.f;
            unsigned short hb = f2bf(v0 + f * (v1 - v0));
            if (k & 1) w4[k >> 1] |= ((unsigned int)hb) << 16;
            else       w4[k >> 1] = hb;
        }
        uint4 st = { w4[0], w4[1], w4[2], w4[3] };
        *(uint4*)(ht + (size_t)(n * 1600 + e) * 256 + c0 + cb) = st;
    }
}

// ------- Kp: finalize BN1 params; W'b = bf16(W*sc); rank-corrections -------
__global__ __launch_bounds__(256) void k_params(const float* __restrict__ w,
                                                const float* __restrict__ bias,
                                                const float* __restrict__ sacc,
                                                const float* __restrict__ qacc,
                                                const float* __restrict__ g,
                                                const float* __restrict__ b,
                                                const float* __restrict__ theta,
                                                unsigned short* __restrict__ wb,
                                                float* __restrict__ b2all,
                                                float* __restrict__ s0v,
                                                float* __restrict__ s63v) {
    int o = blockIdx.x, c = threadIdx.x;
    float mean = sacc[c] * Minv;
    float var  = qacc[c] * Minv - mean * mean;
    float sc = g[c] * rsqrtf(var + EPSV);
    float tc = b[c] - mean * sc;
    float th = theta[c];
    float fd = floorf(th);
    int d = (int)fd;
    float f = th - fd;
    float wv = w[o * 256 + c];
    wb[o * 256 + c] = f2bf(wv * sc);
    float wtc = wv * tc;
    float r0  = (d < 0) ? wtc * (1.f - f) : 0.f;   // t==0 correction (d==-1)
    float r63 = (d == 0) ? wtc * f : 0.f;          // t==63 correction (d==0)
    for (int off = 32; off; off >>= 1) {
        wtc += __shfl_down(wtc, off);
        r0  += __shfl_down(r0, off);
        r63 += __shfl_down(r63, off);
    }
    __shared__ float aux[3][4];
    if ((c & 63) == 0) { int wi = c >> 6; aux[0][wi] = wtc; aux[1][wi] = r0; aux[2][wi] = r63; }
    __syncthreads();
    if (c == 0) {
        b2all[o] = bias[o] + aux[0][0] + aux[0][1] + aux[0][2] + aux[0][3];
        s0v[o]  = aux[1][0] + aux[1][1] + aux[1][2] + aux[1][3];
        s63v[o] = aux[2][0] + aux[2][1] + aux[2][2] + aux[2][3];
    }
}

// ------- K3: y = relu(W' ht + bias2). o=256, j=128, K-step=32, dbuf pipeline -------
// grid (800), block 256 (4 waves). LDS 48KB: 2 x {A[256][32] 16KB + B[128][32] 8KB},
// XOR-granule swizzle (2-way residual). Epilogue: two 128-o passes, C-tile [128][136].
__global__ __launch_bounds__(256) void k_gemm(const unsigned short* __restrict__ ht,
                                              const unsigned short* __restrict__ wb,
                                              const float* __restrict__ b2all,
                                              const float* __restrict__ s0v,
                                              const float* __restrict__ s63v,
                                              unsigned short* __restrict__ y) {
    int j0 = blockIdx.x * 128;
    int tid = threadIdx.x;
    int w = tid >> 6, lane = tid & 63;
    int quad = lane >> 4, l16 = lane & 15;
    __shared__ __attribute__((aligned(16))) unsigned short smem[24576]; // 49,152 B
    floatx4 acc[4][8] = {};
    // staging: per wave 6 gload_lds/K-step; lane (srow=lane>>2, p=lane&3);
    // pre-swizzled SOURCE granule sg = p ^ ((srow>>1)&3); LDS dest stays linear.
    int sg = (lane & 3) ^ ((lane >> 3) & 3);
    const unsigned short* wpA = wb + (size_t)(w * 64 + (lane >> 2)) * 256 + sg * 8;
    const unsigned short* hpB = ht + (size_t)(j0 + w * 32 + (lane >> 2)) * 256 + sg * 8;
    // fragment-read granule: rg = quad ^ ((l16>>1)&3)
    int rg = quad ^ ((l16 >> 1) & 3);

#define STAGE(buf, k0)                                                              \
    {                                                                               \
        unsigned short* Ab_ = smem + (buf) * 12288;                                 \
        unsigned short* Bb_ = Ab_ + 8192;                                           \
        _Pragma("unroll")                                                           \
        for (int a = 0; a < 4; ++a)                                                 \
            gload_lds16(wpA + (size_t)a * 16 * 256 + (k0), Ab_ + (w * 64 + a * 16) * 32); \
        _Pragma("unroll")                                                           \
        for (int b = 0; b < 2; ++b)                                                 \
            gload_lds16(hpB + (size_t)b * 16 * 256 + (k0), Bb_ + (w * 32 + b * 16) * 32); \
    }
#define COMPUTE(buf)                                                                \
    {                                                                               \
        const unsigned short* Ab_ = smem + (buf) * 12288;                           \
        const unsigned short* Bb_ = Ab_ + 8192;                                     \
        short8 af[4];                                                               \
        _Pragma("unroll")                                                           \
        for (int m = 0; m < 4; ++m)                                                 \
            af[m] = *(const short8*)&Ab_[(w * 64 + m * 16 + l16) * 32 + rg * 8];    \
        _Pragma("unroll")                                                           \
        for (int jt = 0; jt < 8; ++jt) {                                            \
            short8 bfr = *(const short8*)&Bb_[(jt * 16 + l16) * 32 + rg * 8];       \
            _Pragma("unroll")                                                       \
            for (int m = 0; m < 4; ++m)                                             \
                acc[m][jt] = __builtin_amdgcn_mfma_f32_16x16x32_bf16(af[m], bfr, acc[m][jt], 0, 0, 0); \
        }                                                                           \
    }

    STAGE(0, 0)
    asm volatile("s_waitcnt vmcnt(0)" ::: "memory");
    __builtin_amdgcn_s_barrier();
#pragma unroll
    for (int t = 0; t < 8; t += 2) {
        if (t + 1 < 8) STAGE(1, (t + 1) * 32)
        COMPUTE(0)
        asm volatile("s_waitcnt vmcnt(0)" ::: "memory");
        __builtin_amdgcn_s_barrier();
        if (t + 2 < 8) STAGE(0, (t + 2) * 32)
        COMPUTE(1)
        asm volatile("s_waitcnt vmcnt(0)" ::: "memory");
        __builtin_amdgcn_s_barrier();
    }
#undef STAGE
#undef COMPUTE

    unsigned short* Cl = smem;             // [128 o][136 pad] bf16 (34,816 B)
    int li = tid & 15, orow = tid >> 4;
#pragma unroll
    for (int p = 0; p < 2; ++p) {
        if ((w >> 1) == p) {
            int rowbase = (w & 1) * 64;
#pragma unroll
            for (int m = 0; m < 4; ++m) {
                int ob = p * 128 + (w & 1) * 64 + m * 16 + quad * 4;
#pragma unroll
                for (int r = 0; r < 4; ++r) {
                    int o = ob + r;
                    float bb = b2all[o], e0 = s0v[o], e63 = s63v[o];
                    int lrow = rowbase + m * 16 + quad * 4 + r;
#pragma unroll
                    for (int jt = 0; jt < 8; ++jt) {
                        int jj = j0 + jt * 16;
                        int nn = jj / 1600;
                        int tvb = jj - nn * 1600 + l16;
                        float bia = bb - (tvb < 25 ? e0 : 0.f) - (tvb >= 1575 ? e63 : 0.f);
                        float v = acc[m][jt][r] + bia;
                        v = v > 0.f ? v : 0.f;
                        Cl[lrow * 136 + jt * 16 + l16] = f2bf(v);
                    }
                }
            }
        }
        __syncthreads();
#pragma unroll
        for (int pass = 0; pass < 8; ++pass) {
            int ol = orow + pass * 16;
            uint4 vv = *(const uint4*)&Cl[ol * 136 + li * 8];
            int o = p * 128 + ol;
            int j = j0 + li * 8;
            int nn = j / 1600;
            int tv = j - nn * 1600;
            *(uint4*)(y + (size_t)nn * CTV + (size_t)o * TV + tv) = vv;
        }
        if (p == 0) __syncthreads();
    }
}

// ------- K4: BN2 analytic partial sums over y (no gather). grid (8 ngrp, 256 o) -------
// acc7: [7][256] = S, Q, P, Y0, Q0, Y63, Q63. 1-deep n prefetch for MLP.
__global__ __launch_bounds__(256) void k_bn2_stats(const unsigned short* __restrict__ y,
                                                   float* __restrict__ acc7) {
    int o = blockIdx.y, ng = blockIdx.x, tid = threadIdx.x;
    float S = 0.f, Q = 0.f, P = 0.f, Y0 = 0.f, Q0 = 0.f, Y63 = 0.f, Q63 = 0.f;
    if (tid < 200) {
        int e = tid * 8;
        int eB = e + 24; if (eB > 1592) eB = 1592;
        int eC = e + 32; if (eC > 1592) eC = 1592;
        const unsigned short* base0 = y + (size_t)(ng * 8) * CTV + (size_t)o * TV;
        uint4 ua = *(const uint4*)(base0 + e);
        uint4 ub = *(const uint4*)(base0 + eB);
        uint4 uc = *(const uint4*)(base0 + eC);
        for (int nn = 0; nn < 8; ++nn) {
            uint4 na, nb, nc;
            if (nn < 7) {
                const unsigned short* row = base0 + (size_t)(nn + 1) * CTV;
                na = *(const uint4*)(row + e);
                nb = *(const uint4*)(row + eB);
                nc = *(const uint4*)(row + eC);
            }
            float a[8], b[8], c[8];
            unp8v(ua, a); unp8v(ub, b); unp8v(uc, c);
#pragma unroll
            for (int k = 0; k < 8; ++k) {
                float v = a[k];
                S += v; Q += v * v;
                float vn = (k < 7) ? b[k + 1] : c[0];     // y[e+k+25]
                if (e + k < 1575) P += v * vn;
            }
            if (e < 32) {
#pragma unroll
                for (int k = 0; k < 8; ++k)
                    if (e + k < 25) { Y0 += a[k]; Q0 += a[k] * a[k]; }
            }
            if (e >= 1568) {
#pragma unroll
                for (int k = 0; k < 8; ++k)
                    if (e + k >= 1575) { Y63 += a[k]; Q63 += a[k] * a[k]; }
            }
            ua = na; ub = nb; uc = nc;
        }
    }
    for (int off = 32; off; off >>= 1) {
        S += __shfl_down(S, off); Q += __shfl_down(Q, off); P += __shfl_down(P, off);
        Y0 += __shfl_down(Y0, off); Q0 += __shfl_down(Q0, off);
        Y63 += __shfl_down(Y63, off); Q63 += __shfl_down(Q63, off);
    }
    if ((tid & 63) == 0) {
        atomicAdd(&acc7[o], S);           atomicAdd(&acc7[256 + o], Q);
        atomicAdd(&acc7[512 + o], P);     atomicAdd(&acc7[768 + o], Y0);
        atomicAdd(&acc7[1024 + o], Q0);   atomicAdd(&acc7[1280 + o], Y63);
        atomicAdd(&acc7[1536 + o], Q63);
    }
}

// ------- K5: out = BN2(shift_out(y)) fp32, div-free masks. grid (64 n, 256 o) -------
__global__ __launch_bounds__(256) void k_bn2_apply(const unsigned short* __restrict__ y,
                                                   const float* __restrict__ theta,
                                                   const float* __restrict__ acc7,
                                                   const float* __restrict__ g,
                                                   const float* __restrict__ b,
                                                   float* __restrict__ out) {
    int o = blockIdx.y, n = blockIdx.x, tid = threadIdx.x;
    float th = theta[o];
    float fd = floorf(th);
    int d = (int)fd;
    float f = th - fd;
    float S = acc7[o], Q = acc7[256 + o], P = acc7[512 + o];
    float Y0 = acc7[768 + o], Q0 = acc7[1024 + o], Y63 = acc7[1280 + o], Q63 = acc7[1536 + o];
    float omf = 1.f - f;
    float sz, qz;
    if (d < 0) { sz = S - omf * Y63; qz = omf * omf * (Q - Q63) + f * f * Q + 2.f * f * omf * P; }
    else       { sz = S - f * Y0;    qz = omf * omf * Q + f * f * (Q - Q0) + 2.f * f * omf * P; }
    float mean = sz * Minv;
    float var = qz * Minv - mean * mean;
    float sc = g[o] * rsqrtf(var + EPSV);
    float tc = b[o] - mean * sc;
    if (tid >= 200) return;
    int e = tid * 8;
    const unsigned short* row = y + (size_t)n * CTV + (size_t)o * TV;
    float a0[8], a1[8];
    if (d < 0) {
        int eA = e - 32; if (eA < 0) eA = 0;
        int eB = e - 24; if (eB < 0) eB = 0;
        float A[8], B[8], M[8];
        unp8v(*(const uint4*)(row + eA), A);
        unp8v(*(const uint4*)(row + eB), B);
        unp8v(*(const uint4*)(row + e), M);
        a0[0] = (e >= 25) ? A[7] : 0.f;     // y[e-25]
#pragma unroll
        for (int k = 1; k < 8; ++k) a0[k] = (e + k >= 25) ? B[k - 1] : 0.f;
#pragma unroll
        for (int k = 0; k < 8; ++k) a1[k] = M[k];
    } else {
        int eB = e + 24; if (eB > 1592) eB = 1592;
        int eC = e + 32; if (eC > 1592) eC = 1592;
        float M[8], B[8], C[8];
        unp8v(*(const uint4*)(row + e), M);
        unp8v(*(const uint4*)(row + eB), B);
        unp8v(*(const uint4*)(row + eC), C);
#pragma unroll
        for (int k = 0; k < 8; ++k) a0[k] = M[k];
#pragma unroll
        for (int k = 0; k < 7; ++k) a1[k] = (e + k < 1575) ? B[k + 1] : 0.f;
        a1[7] = (e + 7 < 1575) ? C[0] : 0.f;
    }
    float4 r0, r1;
#pragma unroll
    for (int k = 0; k < 4; ++k) {
        ((float*)&r0)[k] = (omf * a0[k] + f * a1[k]) * sc + tc;
        ((float*)&r1)[k] = (omf * a0[k + 4] + f * a1[k + 4]) * sc + tc;
    }
    float* op = out + (size_t)n * CTV + (size_t)o * TV + e;
    *(float4*)op = r0;
    *(float4*)(op + 4) = r1;
}

extern "C" void kernel_launch(void* const* d_in, const int* in_sizes, int n_in,
                              void* d_out, int out_size, void* d_ws, size_t ws_size,
                              hipStream_t stream) {
    const float* x      = (const float*)d_in[0];
    const float* conv_w = (const float*)d_in[1];
    const float* conv_b = (const float*)d_in[2];
    const float* bn1_g  = (const float*)d_in[3];
    const float* bn1_b  = (const float*)d_in[4];
    const float* bn2_g  = (const float*)d_in[5];
    const float* bn2_b  = (const float*)d_in[6];
    const float* th_in  = (const float*)d_in[7];
    const float* th_out = (const float*)d_in[8];
    float* out = (float*)d_out;

    char* ws = (char*)d_ws;
    unsigned short* ht = (unsigned short*)ws;                   // 52,428,800 B
    unsigned short* yy = (unsigned short*)(ws + 52428800);      // 52,428,800 B
    unsigned short* wb = (unsigned short*)(ws + 104857600);     // 131,072 B
    float* sacc1 = (float*)(ws + 104988672);
    float* qacc1 = sacc1 + 256;
    float* acc7  = qacc1 + 256;          // 7*256
    float* b2all = acc7 + 7 * 256;
    float* s0v   = b2all + 256;
    float* s63v  = s0v + 256;

    hipMemsetAsync((void*)sacc1, 0, 9 * 256 * sizeof(float), stream);
    hipLaunchKernelGGL(k_stats_shift, dim3(4, 8, 64), dim3(256), 0, stream,
                       x, th_in, sacc1, qacc1, ht);
    hipLaunchKernelGGL(k_params, dim3(256), dim3(256), 0, stream,
                       conv_w, conv_b, sacc1, qacc1, bn1_g, bn1_b, th_in,
                       wb, b2all, s0v, s63v);
    hipLaunchKernelGGL(k_gemm, dim3(800), dim3(256), 0, stream,
                       ht, wb, b2all, s0v, s63v, yy);
    hipLaunchKernelGGL(k_bn2_stats, dim3(8, 256), dim3(256), 0, stream, yy, acc7);
    hipLaunchKernelGGL(k_bn2_apply, dim3(64, 256), dim3(256), 0, stream,
                       yy, th_out, acc7, bn2_g, bn2_b, out);
}